// Round 2
// baseline (583.421 us; speedup 1.0000x reference)
//
#include <hip/hip_runtime.h>
#include <cstdint>
#include <cstddef>

#define DD 256
#define BM 64
#define BN 128
#define MAXR 12

typedef unsigned short u16;
typedef __bf16 bf16t;
typedef bf16t bf16x8 __attribute__((ext_vector_type(8)));
typedef unsigned short us8 __attribute__((ext_vector_type(8)));
typedef float f32x4 __attribute__((ext_vector_type(4)));

__device__ __forceinline__ u16 f2bf(float f) {
    uint32_t u = __builtin_bit_cast(uint32_t, f);
    u += 0x7FFFu + ((u >> 16) & 1u);   // RNE
    return (u16)(u >> 16);
}
__device__ __forceinline__ float bf2f(u16 h) {
    uint32_t u = ((uint32_t)h) << 16;
    return __builtin_bit_cast(float, u);
}

__global__ void k_convert(const float* __restrict__ s, u16* __restrict__ d, int n) {
    int i = blockIdx.x * blockDim.x + threadIdx.x;
    int st = gridDim.x * blockDim.x;
    for (; i < n; i += st) d[i] = f2bf(s[i]);
}

__global__ void k_zero(int* p, int n) {
    int i = blockIdx.x * blockDim.x + threadIdx.x;
    if (i < n) p[i] = 0;
}

// histogram both directions: key_f = dep*R+rel in [0,B), key_r = B + gov*R+rel
__global__ void k_hist2(const int* __restrict__ dep, const int* __restrict__ rel,
                        const int* __restrict__ gov, int E, int R, int B,
                        int* __restrict__ counts) {
    int i = blockIdx.x * blockDim.x + threadIdx.x;
    int st = gridDim.x * blockDim.x;
    for (; i < E; i += st) {
        atomicAdd(&counts[dep[i] * R + rel[i]], 1);
        atomicAdd(&counts[B + gov[i] * R + rel[i]], 1);
    }
}

// phase 1: per-256-block local exclusive scan, block totals to bsum
__global__ void k_scan1(const int* __restrict__ counts, int* __restrict__ csr,
                        int* __restrict__ bsum, int B2) {
    __shared__ int sm[256];
    int tid = threadIdx.x;
    int i = blockIdx.x * 256 + tid;
    int v = (i < B2) ? counts[i] : 0;
    sm[tid] = v;
    __syncthreads();
    for (int off = 1; off < 256; off <<= 1) {
        int t = (tid >= off) ? sm[tid - off] : 0;
        __syncthreads();
        sm[tid] += t;
        __syncthreads();
    }
    if (i < B2) csr[i] = sm[tid] - v;            // local exclusive
    if (tid == 255) bsum[blockIdx.x] = sm[255];  // block total
}

// phase 2: single block scans the block totals (nb <= 2048)
__global__ void k_scan2(const int* __restrict__ bsum, int* __restrict__ bbase, int nb) {
    __shared__ int sm[256];
    int t = threadIdx.x;
    int pre[8];
    int tot = 0;
    for (int j = 0; j < 8; ++j) {
        int idx = t * 8 + j;
        int v = (idx < nb) ? bsum[idx] : 0;
        pre[j] = tot;
        tot += v;
    }
    sm[t] = tot;
    __syncthreads();
    for (int off = 1; off < 256; off <<= 1) {
        int x = (t >= off) ? sm[t - off] : 0;
        __syncthreads();
        sm[t] += x;
        __syncthreads();
    }
    int base = sm[t] - tot;                       // exclusive base for this thread
    for (int j = 0; j < 8; ++j) {
        int idx = t * 8 + j;
        if (idx < nb) bbase[idx] = base + pre[j];
    }
}

// phase 3: add block bases, copy to cursor, set sentinel csr[B2]=2E
__global__ void k_scan3(int* __restrict__ csr, int* __restrict__ cursor,
                        const int* __restrict__ bbase, int B2, int E2) {
    int i = blockIdx.x * 256 + threadIdx.x;
    if (i < B2) {
        int v = csr[i] + bbase[i >> 8];
        csr[i] = v;
        cursor[i] = v;
    }
    if (i == 0) csr[B2] = E2;
}

// scatter: edsrc[pos] = message-source node, bucketed by (dst, rel, dir)
__global__ void k_sortscatter(const int* __restrict__ dep, const int* __restrict__ rel,
                              const int* __restrict__ gov, int E, int R, int B,
                              int* __restrict__ cursor, int* __restrict__ edsrc) {
    int i = blockIdx.x * blockDim.x + threadIdx.x;
    int st = gridDim.x * blockDim.x;
    for (; i < E; i += st) {
        int d = dep[i], g = gov[i], r = rel[i];
        int p = atomicAdd(&cursor[d * R + r], 1);
        edsrc[p] = g;                              // forward: dep <- x[gov]
        int q = atomicAdd(&cursor[B + g * R + r], 1);
        edsrc[q] = d;                              // reverse: gov <- x[dep]
    }
}

// Fused aggregate + dense-K GEMM, no atomics.
// out[d, :] = relu( sum_{s=0..2R+1} W'[s] . agg[d, s, :] )
//   s in [0,R):   agg = sum x[gov] over forward edges (d, rel=s);  W' = W_rel[s]
//   s in [R,2R):  agg = sum x[dep] over reverse edges (d, rel=s-R); W' = W_rel[s]
//   s == 2R:      agg = x[d];                                       W' = W_self
//   s == 2R+1:    agg = [cnt_f(d,.), cnt_r(d,.), 1, 0...];          W' = [b_rel; b_self]
__global__ __launch_bounds__(256, 4)
void k_gemm_fused(const u16* __restrict__ xb, const u16* __restrict__ Wb,
                  const float* __restrict__ b_self, const float* __restrict__ b_rel,
                  const int* __restrict__ csr, const int* __restrict__ edsrc,
                  float* __restrict__ out, int N, int R) {
    __shared__ u16 As[BM][136];                 // 64 rows x 128-k half, stride 68 dw (16B-aligned, bank-optimal)
    __shared__ u16 Bs[BN][72];                  // 128 cols x 64-k,     stride 36 dw
    __shared__ u16 s_offf[BM * MAXR + 1];       // csr offsets rel. to block base (fwd)
    __shared__ u16 s_offr[BM * MAXR + 1];       // (rev)

    const int tid = threadIdx.x;
    const int d0 = blockIdx.x * BM;
    const int n0 = blockIdx.y * BN;
    const int B = N * R;
    const int nk = BM * R;                      // 768 contiguous keys per block

    const int eb0f = csr[d0 * R];
    const int eb0r = csr[B + d0 * R];
    for (int i = tid; i <= nk; i += 256) {
        int kf = d0 * R + i;      if (kf > B) kf = B;
        int kr = B + d0 * R + i;  if (kr > 2 * B) kr = 2 * B;
        s_offf[i] = (u16)(csr[kf] - eb0f);
        s_offr[i] = (u16)(csr[kr] - eb0r);
    }
    __syncthreads();

    f32x4 acc[4][2] = {};
    const int lane = tid & 63;
    const int wave = tid >> 6;                  // wave owns cols [wave*32, wave*32+32)
    const int l15 = lane & 15;
    const int quad = lane >> 4;
    const int S = 2 * R + 2;

    const int arow = tid >> 2, ac = tid & 3;    // A staging: 4 threads/row, 32-u16 chunks
    const int brow = tid >> 1, bh = tid & 1;    // B staging: 2 threads/row, 32-u16 chunks

    const us8 z8 = {0, 0, 0, 0, 0, 0, 0, 0};

    for (int s = 0; s < S; ++s) {
        const bool biasSlot = (s == 2 * R + 1);
        const int khmax = biasSlot ? 1 : 2;
        const int kqmax = biasSlot ? 1 : 2;
        for (int kh = 0; kh < khmax; ++kh) {
            // ---- stage A (one 128-wide K half, aggregated on the fly) ----
            {
                const int koff = kh * 128 + ac * 32;
                us8* dst = (us8*)&As[arow][ac * 32];
                const int d = d0 + arow;
                if (biasSlot) {
                    if (ac == 0) {
                        #pragma unroll
                        for (int g = 0; g < 4; ++g) {
                            u16 tmp[8];
                            #pragma unroll
                            for (int t2 = 0; t2 < 8; ++t2) {
                                int ii = g * 8 + t2;
                                float v = 0.0f;
                                if (ii < R)
                                    v = (float)(s_offf[arow * R + ii + 1] - s_offf[arow * R + ii]);
                                else if (ii < 2 * R)
                                    v = (float)(s_offr[arow * R + (ii - R) + 1] - s_offr[arow * R + (ii - R)]);
                                else if (ii == 2 * R)
                                    v = 1.0f;
                                tmp[t2] = f2bf(v);
                            }
                            dst[g] = *(const us8*)tmp;
                        }
                    } else {
                        dst[0] = z8; dst[1] = z8; dst[2] = z8; dst[3] = z8;
                    }
                } else {
                    int cnt, sbase = 0, beg = 0;
                    if (s < R) {
                        int b0 = arow * R + s;
                        beg = s_offf[b0]; cnt = s_offf[b0 + 1] - beg; sbase = eb0f;
                    } else if (s < 2 * R) {
                        int b0 = arow * R + (s - R);
                        beg = s_offr[b0]; cnt = s_offr[b0 + 1] - beg; sbase = eb0r;
                    } else {
                        cnt = (d < N) ? 1 : 0;
                    }
                    if (cnt == 0) {
                        dst[0] = z8; dst[1] = z8; dst[2] = z8; dst[3] = z8;
                    } else {
                        const int src0 = (s < 2 * R) ? edsrc[sbase + beg] : d;
                        const us8* gp = (const us8*)(xb + (size_t)src0 * DD + koff);
                        us8 g0 = gp[0], g1 = gp[1], g2 = gp[2], g3 = gp[3];
                        if (cnt == 1) {
                            dst[0] = g0; dst[1] = g1; dst[2] = g2; dst[3] = g3;
                        } else {
                            us8 gv[4] = {g0, g1, g2, g3};
                            #pragma unroll
                            for (int grp = 0; grp < 4; ++grp) {
                                float fa[8];
                                #pragma unroll
                                for (int t2 = 0; t2 < 8; ++t2) fa[t2] = bf2f(gv[grp][t2]);
                                for (int j = 1; j < cnt; ++j) {
                                    int sj = edsrc[sbase + beg + j];
                                    us8 gj = *(const us8*)(xb + (size_t)sj * DD + koff + grp * 8);
                                    #pragma unroll
                                    for (int t2 = 0; t2 < 8; ++t2) fa[t2] += bf2f(gj[t2]);
                                }
                                u16 tmp[8];
                                #pragma unroll
                                for (int t2 = 0; t2 < 8; ++t2) tmp[t2] = f2bf(fa[t2]);
                                dst[grp] = *(const us8*)tmp;
                            }
                        }
                    }
                }
            }
            for (int kq = 0; kq < kqmax; ++kq) {
                // ---- stage B (64-k slab of W'[s], cols n0..n0+127) ----
                {
                    const int kg = kh * 128 + kq * 64 + bh * 32;
                    us8* dst = (us8*)&Bs[brow][bh * 32];
                    const int n = n0 + brow;
                    if (!biasSlot) {
                        const us8* gp = (const us8*)(Wb + (size_t)s * (DD * DD) + (size_t)n * DD + kg);
                        dst[0] = gp[0]; dst[1] = gp[1]; dst[2] = gp[2]; dst[3] = gp[3];
                    } else if (kg == 0) {
                        #pragma unroll
                        for (int g = 0; g < 4; ++g) {
                            u16 tmp[8];
                            #pragma unroll
                            for (int t2 = 0; t2 < 8; ++t2) {
                                int ii = g * 8 + t2;
                                float v = 0.0f;
                                if (ii < 2 * R) v = b_rel[ii * DD + n];
                                else if (ii == 2 * R) v = b_self[n];
                                tmp[t2] = f2bf(v);
                            }
                            dst[g] = *(const us8*)tmp;
                        }
                    } else {
                        dst[0] = z8; dst[1] = z8; dst[2] = z8; dst[3] = z8;
                    }
                }
                __syncthreads();
                // ---- MFMA on this 64-k slab ----
                #pragma unroll
                for (int ks = 0; ks < 2; ++ks) {
                    const int kA = kq * 64 + ks * 32 + quad * 8;
                    const int kB = ks * 32 + quad * 8;
                    bf16x8 af[4], bfv[2];
                    #pragma unroll
                    for (int mt = 0; mt < 4; ++mt)
                        af[mt] = __builtin_bit_cast(bf16x8, *(const us8*)&As[mt * 16 + l15][kA]);
                    #pragma unroll
                    for (int nt = 0; nt < 2; ++nt)
                        bfv[nt] = __builtin_bit_cast(bf16x8, *(const us8*)&Bs[wave * 32 + nt * 16 + l15][kB]);
                    #pragma unroll
                    for (int mt = 0; mt < 4; ++mt)
                        #pragma unroll
                        for (int nt = 0; nt < 2; ++nt)
                            acc[mt][nt] = __builtin_amdgcn_mfma_f32_16x16x32_bf16(
                                af[mt], bfv[nt], acc[mt][nt], 0, 0, 0);
                }
                __syncthreads();
            }
        }
    }

    // epilogue: relu + plain store (C/D layout col=lane&15, row=quad*4+reg)
    #pragma unroll
    for (int nt = 0; nt < 2; ++nt) {
        const int n = n0 + wave * 32 + nt * 16 + l15;
        #pragma unroll
        for (int mt = 0; mt < 4; ++mt) {
            #pragma unroll
            for (int j = 0; j < 4; ++j) {
                const int m = mt * 16 + quad * 4 + j;
                const int d = d0 + m;
                if (d < N) out[(size_t)d * DD + n] = fmaxf(acc[mt][nt][j], 0.0f);
            }
        }
    }
}

extern "C" void kernel_launch(void* const* d_in, const int* in_sizes, int n_in,
                              void* d_out, int out_size, void* d_ws, size_t ws_size,
                              hipStream_t stream) {
    const float* x      = (const float*)d_in[0];
    const int*   dep    = (const int*)  d_in[1];
    const int*   rel    = (const int*)  d_in[2];
    const int*   gov    = (const int*)  d_in[3];
    const float* W_self = (const float*)d_in[4];
    const float* b_self = (const float*)d_in[5];
    const float* W_rel  = (const float*)d_in[6];
    const float* b_rel  = (const float*)d_in[7];
    float* out = (float*)d_out;

    const int N  = in_sizes[0] / DD;     // 20000
    const int E  = in_sizes[1];          // 200000
    const int R2 = in_sizes[7] / DD;     // 24
    const int R  = R2 / 2;               // 12
    const int B  = N * R;                // 240000 buckets per direction
    const int B2 = 2 * B;

    char* w = (char*)d_ws;
    auto alloc = [&](size_t bytes) {
        char* p = w;
        w += (bytes + 255) & ~(size_t)255;
        return p;
    };
    u16* xb     = (u16*)alloc((size_t)N * DD * sizeof(u16));
    u16* Wb     = (u16*)alloc((size_t)(R2 + 1) * DD * DD * sizeof(u16));
    int* counts = (int*)alloc((size_t)B2 * sizeof(int));
    int* csr    = (int*)alloc((size_t)(B2 + 1) * sizeof(int));
    int* cursor = (int*)alloc((size_t)B2 * sizeof(int));
    int* bsum   = (int*)alloc((size_t)2048 * sizeof(int));
    int* bbase  = (int*)alloc((size_t)2048 * sizeof(int));
    int* edsrc  = (int*)alloc((size_t)2 * E * sizeof(int));

    // 1. bf16 conversions (x; W_rel slots 0..2R-1; W_self slot 2R)
    k_convert<<<1024, 256, 0, stream>>>(x, xb, N * DD);
    k_convert<<<1024, 256, 0, stream>>>(W_rel, Wb, R2 * DD * DD);
    k_convert<<<64, 256, 0, stream>>>(W_self, Wb + (size_t)R2 * DD * DD, DD * DD);

    // 2. counting-sort edges by (dst, rel, dir) -> CSR + edsrc
    const int scanBlocks = (B2 + 255) / 256;     // 1875
    k_zero<<<scanBlocks, 256, 0, stream>>>(counts, B2);
    k_hist2<<<256, 256, 0, stream>>>(dep, rel, gov, E, R, B, counts);
    k_scan1<<<scanBlocks, 256, 0, stream>>>(counts, csr, bsum, B2);
    k_scan2<<<1, 256, 0, stream>>>(bsum, bbase, scanBlocks);
    k_scan3<<<scanBlocks, 256, 0, stream>>>(csr, cursor, bbase, B2, 2 * E);
    k_sortscatter<<<(E + 255) / 256, 256, 0, stream>>>(dep, rel, gov, E, R, B, cursor, edsrc);

    // 3. fused aggregate + GEMM + bias + relu (one kernel, no atomics)
    dim3 grid((N + BM - 1) / BM, DD / BN, 1);    // 313 x 2
    k_gemm_fused<<<grid, 256, 0, stream>>>(xb, Wb, b_self, b_rel, csr, edsrc, out, N, R);
}

// Round 4
// 547.917 us; speedup vs baseline: 1.0648x; 1.0648x over previous
//
#include <hip/hip_runtime.h>
#include <cstdint>
#include <cstddef>

#define DD 256

typedef unsigned short u16;
typedef __bf16 bf16t;
typedef bf16t bf16x8 __attribute__((ext_vector_type(8)));
typedef unsigned short us8 __attribute__((ext_vector_type(8)));
typedef unsigned short us4 __attribute__((ext_vector_type(4)));
typedef float f32x4 __attribute__((ext_vector_type(4)));

__device__ __forceinline__ u16 f2bf(float f) {
    uint32_t u = __builtin_bit_cast(uint32_t, f);
    u += 0x7FFFu + ((u >> 16) & 1u);   // RNE
    return (u16)(u >> 16);
}
__device__ __forceinline__ float bf2f(u16 h) {
    uint32_t u = ((uint32_t)h) << 16;
    return __builtin_bit_cast(float, u);
}

__global__ void k_convert(const float* __restrict__ s, u16* __restrict__ d, int n) {
    int i = blockIdx.x * blockDim.x + threadIdx.x;
    int st = gridDim.x * blockDim.x;
    for (; i < n; i += st) d[i] = f2bf(s[i]);
}

// Wb slot 2R+1 = bias matrix: B25[n][k'] = k'<2R ? b_rel[k'][n] : (k'==2R ? b_self[n] : 0)
__global__ void k_biasmat(const float* __restrict__ b_self, const float* __restrict__ b_rel,
                          u16* __restrict__ dst, int R2) {
    int i = blockIdx.x * 256 + threadIdx.x;   // i = n*256 + k'
    int n = i >> 8, k = i & 255;
    float v = 0.0f;
    if (k < R2) v = b_rel[k * DD + n];
    else if (k == R2) v = b_self[n];
    dst[i] = f2bf(v);
}

__global__ void k_zero(int* p, int n) {
    int i = blockIdx.x * blockDim.x + threadIdx.x;
    if (i < n) p[i] = 0;
}

// histogram both directions: key_f = dep*R+rel in [0,B), key_r = B + gov*R+rel
__global__ void k_hist2(const int* __restrict__ dep, const int* __restrict__ rel,
                        const int* __restrict__ gov, int E, int R, int B,
                        int* __restrict__ counts) {
    int i = blockIdx.x * blockDim.x + threadIdx.x;
    int st = gridDim.x * blockDim.x;
    for (; i < E; i += st) {
        atomicAdd(&counts[dep[i] * R + rel[i]], 1);
        atomicAdd(&counts[B + gov[i] * R + rel[i]], 1);
    }
}

__global__ void k_scan1(const int* __restrict__ counts, int* __restrict__ csr,
                        int* __restrict__ bsum, int B2) {
    __shared__ int sm[256];
    int tid = threadIdx.x;
    int i = blockIdx.x * 256 + tid;
    int v = (i < B2) ? counts[i] : 0;
    sm[tid] = v;
    __syncthreads();
    for (int off = 1; off < 256; off <<= 1) {
        int t = (tid >= off) ? sm[tid - off] : 0;
        __syncthreads();
        sm[tid] += t;
        __syncthreads();
    }
    if (i < B2) csr[i] = sm[tid] - v;
    if (tid == 255) bsum[blockIdx.x] = sm[255];
}

__global__ void k_scan2(const int* __restrict__ bsum, int* __restrict__ bbase, int nb) {
    __shared__ int sm[256];
    int t = threadIdx.x;
    int pre[8];
    int tot = 0;
    for (int j = 0; j < 8; ++j) {
        int idx = t * 8 + j;
        int v = (idx < nb) ? bsum[idx] : 0;
        pre[j] = tot;
        tot += v;
    }
    sm[t] = tot;
    __syncthreads();
    for (int off = 1; off < 256; off <<= 1) {
        int x = (t >= off) ? sm[t - off] : 0;
        __syncthreads();
        sm[t] += x;
        __syncthreads();
    }
    int base = sm[t] - tot;
    for (int j = 0; j < 8; ++j) {
        int idx = t * 8 + j;
        if (idx < nb) bbase[idx] = base + pre[j];
    }
}

__global__ void k_scan3(int* __restrict__ csr, int* __restrict__ cursor,
                        const int* __restrict__ bbase, int B2, int E2) {
    int i = blockIdx.x * 256 + threadIdx.x;
    if (i < B2) {
        int v = csr[i] + bbase[i >> 8];
        csr[i] = v;
        cursor[i] = v;
    }
    if (i == 0) csr[B2] = E2;
}

__global__ void k_sortscatter(const int* __restrict__ dep, const int* __restrict__ rel,
                              const int* __restrict__ gov, int E, int R, int B,
                              int* __restrict__ cursor, int* __restrict__ edsrc) {
    int i = blockIdx.x * blockDim.x + threadIdx.x;
    int st = gridDim.x * blockDim.x;
    for (; i < E; i += st) {
        int d = dep[i], g = gov[i], r = rel[i];
        int p = atomicAdd(&cursor[d * R + r], 1);
        edsrc[p] = g;                              // forward: dep <- x[gov]
        int q = atomicAdd(&cursor[B + g * R + r], 1);
        edsrc[q] = d;                              // reverse: gov <- x[dep]
    }
}

// Aggregation: one WAVE per (d, s) pair; lanes parallel over 256 feats (us4 = 4 bf16).
//   s in [0,R):   sum x[gov] over forward edges (d, rel=s)
//   s in [R,2R):  sum x[dep] over reverse edges (d, rel=s-R)
//   s == 2R:      x[d]
//   s == 2R+1:    [cnt_f, cnt_r, 1, 0...]
// agg row-major [cs][S*256]
__global__ __launch_bounds__(256) void k_agg(
    const u16* __restrict__ xb, const int* __restrict__ csr,
    const int* __restrict__ edsrc, u16* __restrict__ agg,
    int d0, int cs, int R, int B) {
    const int S = 2 * R + 2;
    int wid = (blockIdx.x * 256 + threadIdx.x) >> 6;
    if (wid >= cs * S) return;
    int lane = threadIdx.x & 63;
    int dl = wid / S;
    int s = wid - dl * S;
    int d = d0 + dl;
    us4* dst = (us4*)(agg + (size_t)dl * (S * DD) + s * DD + lane * 4);
    if (s < 2 * R) {
        int key = (s < R) ? (d * R + s) : (B + d * R + (s - R));
        int beg = csr[key], end = csr[key + 1];
        int cnt = end - beg;
        if (cnt == 0) {
            us4 z = {0, 0, 0, 0};
            *dst = z;
        } else if (cnt == 1) {
            int src = edsrc[beg];
            *dst = *(const us4*)(xb + (size_t)src * DD + lane * 4);
        } else {
            float a0 = 0, a1 = 0, a2 = 0, a3 = 0;
            for (int j = beg; j < end; ++j) {
                int src = edsrc[j];
                us4 v = *(const us4*)(xb + (size_t)src * DD + lane * 4);
                a0 += bf2f(v[0]); a1 += bf2f(v[1]); a2 += bf2f(v[2]); a3 += bf2f(v[3]);
            }
            us4 o;
            o[0] = f2bf(a0); o[1] = f2bf(a1); o[2] = f2bf(a2); o[3] = f2bf(a3);
            *dst = o;
        }
    } else if (s == 2 * R) {
        *dst = *(const us4*)(xb + (size_t)d * DD + lane * 4);
    } else {
        us4 o;
        #pragma unroll
        for (int t = 0; t < 4; ++t) {
            int k = lane * 4 + t;
            float v = 0.0f;
            if (k < R) v = (float)(csr[d * R + k + 1] - csr[d * R + k]);
            else if (k < 2 * R) v = (float)(csr[B + d * R + (k - R) + 1] - csr[B + d * R + (k - R)]);
            else if (k == 2 * R) v = 1.0f;
            o[t] = f2bf(v);
        }
        *dst = o;
    }
}

// Dense GEMM: out[d0+m, n] = relu( sum_k A[m,k] * W'[n,k] ), K = 26*256 = 6656.
// 128x128 tile, 512 threads = 8 waves, each wave a 32x64 sub-tile.
// grid: x = n-tile (2, fastest -> A-slab shared by co-resident pair), y = m-tile.
#define LDA 72
__global__ __launch_bounds__(512) void k_dense(
    const u16* __restrict__ A, const u16* __restrict__ Wb,
    float* __restrict__ out, int d0, int cs, int K) {
    __shared__ u16 As[128][LDA];
    __shared__ u16 Bs[128][LDA];
    const int tid = threadIdx.x;
    const int n0 = blockIdx.x * 128;
    const int m0 = blockIdx.y * 128;

    const int lane = tid & 63;
    const int wv = tid >> 6;
    const int wr = wv & 3;          // row group: rows wr*32 .. +32
    const int wc = wv >> 2;         // col group: cols wc*64 .. +64
    const int l15 = lane & 15, quad = lane >> 4;

    // staging: threads 0..255 stage A, 256..511 stage B; each: row st>>1, 32-u16 half
    const int sgrp = tid >> 8;            // 0 = A, 1 = B
    const int st = tid & 255;
    const int srow = st >> 1, sh = (st & 1) * 32;
    int arow = m0 + srow;
    if (arow >= cs) arow = 0;             // clamp: row only affects discarded output
    const u16* agp = A + (size_t)arow * K + sh;   // + kb each iter
    const int brow = n0 + srow;

    f32x4 acc[2][4] = {};

    for (int kb = 0; kb < K; kb += 64) {
        if (sgrp == 0) {
            const us8* g = (const us8*)(agp + kb);
            us8 v0 = g[0], v1 = g[1], v2 = g[2], v3 = g[3];
            *(us8*)&As[srow][sh]      = v0;
            *(us8*)&As[srow][sh + 8]  = v1;
            *(us8*)&As[srow][sh + 16] = v2;
            *(us8*)&As[srow][sh + 24] = v3;
        } else {
            int kg = kb + sh;
            const u16* g = Wb + ((size_t)(kg >> 8) << 16) + (size_t)brow * DD + (kg & 255);
            us8 v0 = ((const us8*)g)[0], v1 = ((const us8*)g)[1];
            us8 v2 = ((const us8*)g)[2], v3 = ((const us8*)g)[3];
            *(us8*)&Bs[srow][sh]      = v0;
            *(us8*)&Bs[srow][sh + 8]  = v1;
            *(us8*)&Bs[srow][sh + 16] = v2;
            *(us8*)&Bs[srow][sh + 24] = v3;
        }
        __syncthreads();
        #pragma unroll
        for (int ks = 0; ks < 2; ++ks) {
            const int kk = ks * 32 + quad * 8;
            bf16x8 af[2], bfv[4];
            #pragma unroll
            for (int mt = 0; mt < 2; ++mt)
                af[mt] = __builtin_bit_cast(bf16x8, *(const us8*)&As[wr * 32 + mt * 16 + l15][kk]);
            #pragma unroll
            for (int nt = 0; nt < 4; ++nt)
                bfv[nt] = __builtin_bit_cast(bf16x8, *(const us8*)&Bs[wc * 64 + nt * 16 + l15][kk]);
            #pragma unroll
            for (int mt = 0; mt < 2; ++mt)
                #pragma unroll
                for (int nt = 0; nt < 4; ++nt)
                    acc[mt][nt] = __builtin_amdgcn_mfma_f32_16x16x32_bf16(
                        af[mt], bfv[nt], acc[mt][nt], 0, 0, 0);
        }
        __syncthreads();
    }

    // epilogue: relu + plain store (C/D layout: col=lane&15, row=quad*4+reg)
    #pragma unroll
    for (int nt = 0; nt < 4; ++nt) {
        const int n = n0 + wc * 64 + nt * 16 + l15;
        #pragma unroll
        for (int mt = 0; mt < 2; ++mt) {
            #pragma unroll
            for (int j = 0; j < 4; ++j) {
                const int m = wr * 32 + mt * 16 + quad * 4 + j;
                const int ml = m0 + m;
                if (ml < cs) out[(size_t)(d0 + ml) * DD + n] = fmaxf(acc[mt][nt][j], 0.0f);
            }
        }
    }
}

extern "C" void kernel_launch(void* const* d_in, const int* in_sizes, int n_in,
                              void* d_out, int out_size, void* d_ws, size_t ws_size,
                              hipStream_t stream) {
    const float* x      = (const float*)d_in[0];
    const int*   dep    = (const int*)  d_in[1];
    const int*   rel    = (const int*)  d_in[2];
    const int*   gov    = (const int*)  d_in[3];
    const float* W_self = (const float*)d_in[4];
    const float* b_self = (const float*)d_in[5];
    const float* W_rel  = (const float*)d_in[6];
    const float* b_rel  = (const float*)d_in[7];
    float* out = (float*)d_out;

    const int N  = in_sizes[0] / DD;     // 20000
    const int E  = in_sizes[1];          // 200000
    const int R2 = in_sizes[7] / DD;     // 24
    const int R  = R2 / 2;               // 12
    const int B  = N * R;                // 240000
    const int B2 = 2 * B;
    const int S  = R2 + 2;               // 26 slots
    const int K  = S * DD;               // 6656

    char* w = (char*)d_ws;
    auto alloc = [&](size_t bytes) {
        char* p = w;
        w += (bytes + 255) & ~(size_t)255;
        return p;
    };
    u16* xb     = (u16*)alloc((size_t)N * DD * sizeof(u16));
    u16* Wb     = (u16*)alloc((size_t)S * DD * DD * sizeof(u16));  // [0..2R)=W_rel, 2R=W_self, 2R+1=bias
    int* counts = (int*)alloc((size_t)B2 * sizeof(int));
    int* csr    = (int*)alloc((size_t)(B2 + 1) * sizeof(int));
    int* cursor = (int*)alloc((size_t)B2 * sizeof(int));
    int* bsum   = (int*)alloc((size_t)2048 * sizeof(int));
    int* bbase  = (int*)alloc((size_t)2048 * sizeof(int));
    int* edsrc  = (int*)alloc((size_t)2 * E * sizeof(int));

    // agg buffer: as many 128-row chunks as fit
    size_t used = (size_t)(w - (char*)d_ws);
    size_t avail = (ws_size > used) ? (ws_size - used) : 0;
    int Mpad = ((N + 127) / 128) * 128;
    int cap = (int)((avail / ((size_t)K * sizeof(u16))) / 128) * 128;
    if (cap > Mpad) cap = Mpad;
    if (cap < 128) cap = 128;
    u16* agg = (u16*)w;

    // 1. bf16 conversions + bias matrix
    k_convert<<<1024, 256, 0, stream>>>(x, xb, N * DD);
    k_convert<<<1024, 256, 0, stream>>>(W_rel, Wb, R2 * DD * DD);
    k_convert<<<64, 256, 0, stream>>>(W_self, Wb + (size_t)R2 * DD * DD, DD * DD);
    k_biasmat<<<DD, 256, 0, stream>>>(b_self, b_rel, Wb + (size_t)(R2 + 1) * DD * DD, R2);

    // 2. counting-sort edges by (dst, rel, dir) -> CSR + edsrc
    const int scanBlocks = (B2 + 255) / 256;
    k_zero<<<scanBlocks, 256, 0, stream>>>(counts, B2);
    k_hist2<<<256, 256, 0, stream>>>(dep, rel, gov, E, R, B, counts);
    k_scan1<<<scanBlocks, 256, 0, stream>>>(counts, csr, bsum, B2);
    k_scan2<<<1, 256, 0, stream>>>(bsum, bbase, scanBlocks);
    k_scan3<<<scanBlocks, 256, 0, stream>>>(csr, cursor, bbase, B2, 2 * E);
    k_sortscatter<<<(E + 255) / 256, 256, 0, stream>>>(dep, rel, gov, E, R, B, cursor, edsrc);

    // 3. per chunk: aggregate (d,s) buckets -> dense GEMM + bias + relu
    for (int d0 = 0; d0 < N; d0 += cap) {
        int cs = (N - d0 < cap) ? (N - d0) : cap;
        int waves = cs * S;
        k_agg<<<(waves + 3) / 4, 256, 0, stream>>>(xb, csr, edsrc, agg, d0, cs, R, B);
        dim3 g(2, (cs + 127) / 128, 1);
        k_dense<<<g, 512, 0, stream>>>(agg, Wb, out, d0, cs, K);
    }
}

// Round 5
// 464.064 us; speedup vs baseline: 1.2572x; 1.1807x over previous
//
#include <hip/hip_runtime.h>
#include <cstdint>
#include <cstddef>

#define DD 256

typedef unsigned short u16;
typedef __bf16 bf16t;
typedef bf16t bf16x8 __attribute__((ext_vector_type(8)));
typedef unsigned short us8 __attribute__((ext_vector_type(8)));
typedef float f32x4 __attribute__((ext_vector_type(4)));

__device__ __forceinline__ u16 f2bf(float f) {
    uint32_t u = __builtin_bit_cast(uint32_t, f);
    u += 0x7FFFu + ((u >> 16) & 1u);   // RNE
    return (u16)(u >> 16);
}
__device__ __forceinline__ float bf2f(u16 h) {
    uint32_t u = ((uint32_t)h) << 16;
    return __builtin_bit_cast(float, u);
}

__global__ void k_convert(const float* __restrict__ s, u16* __restrict__ d, int n) {
    int i = blockIdx.x * blockDim.x + threadIdx.x;
    int st = gridDim.x * blockDim.x;
    for (; i < n; i += st) d[i] = f2bf(s[i]);
}

// Wb slot 2R+1 = bias matrix: B25[n][k'] = k'<2R ? b_rel[k'][n] : (k'==2R ? b_self[n] : 0)
__global__ void k_biasmat(const float* __restrict__ b_self, const float* __restrict__ b_rel,
                          u16* __restrict__ dst, int R2) {
    int i = blockIdx.x * 256 + threadIdx.x;   // i = n*256 + k'
    int n = i >> 8, k = i & 255;
    float v = 0.0f;
    if (k < R2) v = b_rel[k * DD + n];
    else if (k == R2) v = b_self[n];
    dst[i] = f2bf(v);
}

__global__ void k_zero(int* p, int n) {
    int i = blockIdx.x * blockDim.x + threadIdx.x;
    if (i < n) p[i] = 0;
}

// histogram both directions: key_f = dep*R+rel in [0,B), key_r = B + gov*R+rel
__global__ void k_hist2(const int* __restrict__ dep, const int* __restrict__ rel,
                        const int* __restrict__ gov, int E, int R, int B,
                        int* __restrict__ counts) {
    int i = blockIdx.x * blockDim.x + threadIdx.x;
    int st = gridDim.x * blockDim.x;
    for (; i < E; i += st) {
        atomicAdd(&counts[dep[i] * R + rel[i]], 1);
        atomicAdd(&counts[B + gov[i] * R + rel[i]], 1);
    }
}

__global__ void k_scan1(const int* __restrict__ counts, int* __restrict__ csr,
                        int* __restrict__ bsum, int B2) {
    __shared__ int sm[256];
    int tid = threadIdx.x;
    int i = blockIdx.x * 256 + tid;
    int v = (i < B2) ? counts[i] : 0;
    sm[tid] = v;
    __syncthreads();
    for (int off = 1; off < 256; off <<= 1) {
        int t = (tid >= off) ? sm[tid - off] : 0;
        __syncthreads();
        sm[tid] += t;
        __syncthreads();
    }
    if (i < B2) csr[i] = sm[tid] - v;
    if (tid == 255) bsum[blockIdx.x] = sm[255];
}

__global__ void k_scan2(const int* __restrict__ bsum, int* __restrict__ bbase, int nb) {
    __shared__ int sm[256];
    int t = threadIdx.x;
    int pre[8];
    int tot = 0;
    for (int j = 0; j < 8; ++j) {
        int idx = t * 8 + j;
        int v = (idx < nb) ? bsum[idx] : 0;
        pre[j] = tot;
        tot += v;
    }
    sm[t] = tot;
    __syncthreads();
    for (int off = 1; off < 256; off <<= 1) {
        int x = (t >= off) ? sm[t - off] : 0;
        __syncthreads();
        sm[t] += x;
        __syncthreads();
    }
    int base = sm[t] - tot;
    for (int j = 0; j < 8; ++j) {
        int idx = t * 8 + j;
        if (idx < nb) bbase[idx] = base + pre[j];
    }
}

__global__ void k_scan3(int* __restrict__ csr, int* __restrict__ cursor,
                        const int* __restrict__ bbase, int B2, int E2) {
    int i = blockIdx.x * 256 + threadIdx.x;
    if (i < B2) {
        int v = csr[i] + bbase[i >> 8];
        csr[i] = v;
        cursor[i] = v;
    }
    if (i == 0) csr[B2] = E2;
}

__global__ void k_sortscatter(const int* __restrict__ dep, const int* __restrict__ rel,
                              const int* __restrict__ gov, int E, int R, int B,
                              int* __restrict__ cursor, int* __restrict__ edsrc) {
    int i = blockIdx.x * blockDim.x + threadIdx.x;
    int st = gridDim.x * blockDim.x;
    for (; i < E; i += st) {
        int d = dep[i], g = gov[i], r = rel[i];
        int p = atomicAdd(&cursor[d * R + r], 1);
        edsrc[p] = g;                              // forward: dep <- x[gov]
        int q = atomicAdd(&cursor[B + g * R + r], 1);
        edsrc[q] = d;                              // reverse: gov <- x[dep]
    }
}

// Aggregation: one HALF-WAVE (32 lanes x us8 = 512 B row) per (d, s) bucket.
//   s in [0,R):   sum x[gov] over forward edges (d, rel=s)
//   s in [R,2R):  sum x[dep] over reverse edges (d, rel=s-R)
//   s == 2R:      x[d]
//   s == 2R+1:    [cnt_f, cnt_r, 1, 0...]
// agg row-major [cs][S*256]
__global__ __launch_bounds__(256) void k_agg(
    const u16* __restrict__ xb, const int* __restrict__ csr,
    const int* __restrict__ edsrc, u16* __restrict__ agg,
    int d0, int cs, int R, int B) {
    const int S = 2 * R + 2;
    int hw = (blockIdx.x * 256 + threadIdx.x) >> 5;   // halfwave id
    if (hw >= cs * S) return;
    int l = threadIdx.x & 31;                          // lane within halfwave
    int dl = hw / S;
    int s = hw - dl * S;
    int d = d0 + dl;
    us8* dst = (us8*)(agg + (size_t)dl * (S * DD) + s * DD + l * 8);
    if (s < 2 * R) {
        int key = (s < R) ? (d * R + s) : (B + d * R + (s - R));
        int beg = csr[key], end = csr[key + 1];
        int cnt = end - beg;
        if (cnt == 0) {
            us8 z = {0, 0, 0, 0, 0, 0, 0, 0};
            *dst = z;
        } else if (cnt == 1) {
            int src = edsrc[beg];
            *dst = *(const us8*)(xb + (size_t)src * DD + l * 8);
        } else {
            int src = edsrc[beg];
            us8 v = *(const us8*)(xb + (size_t)src * DD + l * 8);
            float fa[8];
            #pragma unroll
            for (int t = 0; t < 8; ++t) fa[t] = bf2f(v[t]);
            for (int j = beg + 1; j < end; ++j) {
                int sj = edsrc[j];
                us8 vj = *(const us8*)(xb + (size_t)sj * DD + l * 8);
                #pragma unroll
                for (int t = 0; t < 8; ++t) fa[t] += bf2f(vj[t]);
            }
            us8 o;
            #pragma unroll
            for (int t = 0; t < 8; ++t) o[t] = f2bf(fa[t]);
            *dst = o;
        }
    } else if (s == 2 * R) {
        *dst = *(const us8*)(xb + (size_t)d * DD + l * 8);
    } else {
        us8 o;
        #pragma unroll
        for (int t = 0; t < 8; ++t) {
            int k = l * 8 + t;
            float v = 0.0f;
            if (k < R) v = (float)(csr[d * R + k + 1] - csr[d * R + k]);
            else if (k < 2 * R) v = (float)(csr[B + d * R + (k - R) + 1] - csr[B + d * R + (k - R)]);
            else if (k == 2 * R) v = 1.0f;
            o[t] = f2bf(v);
        }
        *dst = o;
    }
}

// Dense GEMM: out[d0+m, n] = relu( sum_k A[m,k] * W'[n,k] ), K = 26*256 = 6656.
// 64x128 tile, 256 threads = 4 waves, each wave a 32x64 sub-tile.
// grid: x = n-tile (2, fastest -> A-slab shared by co-resident pair), y = m-tile (313).
// 626 blocks -> ~2.4-5 blocks/CU for cross-block latency overlap.
#define LDA 72
__global__ __launch_bounds__(256) void k_dense(
    const u16* __restrict__ A, const u16* __restrict__ Wb,
    float* __restrict__ out, int d0, int cs, int K) {
    __shared__ u16 As[64][LDA];
    __shared__ u16 Bs[128][LDA];
    const int tid = threadIdx.x;
    const int n0 = blockIdx.x * 128;
    const int m0 = blockIdx.y * 64;

    const int lane = tid & 63;
    const int wv = tid >> 6;
    const int wr = wv & 1;          // row group: rows wr*32 .. +32
    const int wc = wv >> 1;         // col group: cols wc*64 .. +64
    const int l15 = lane & 15, quad = lane >> 4;

    // A staging: thread t -> row t>>2, 16-u16 chunk (t&3)*16  (64 rows x 64 k)
    const int sar = tid >> 2, sac = (tid & 3) * 16;
    int arow = m0 + sar;
    if (arow >= cs) arow = 0;             // clamp: row only affects discarded output
    const u16* agp = A + (size_t)arow * K + sac;
    // B staging: thread t -> row t>>1, 32-u16 chunk (t&1)*32  (128 rows x 64 k)
    const int sbr = tid >> 1, sbc = (tid & 1) * 32;
    const int brow = n0 + sbr;

    f32x4 acc[2][4] = {};

    for (int kb = 0; kb < K; kb += 64) {
        {
            const us8* g = (const us8*)(agp + kb);
            us8 v0 = g[0], v1 = g[1];
            *(us8*)&As[sar][sac]     = v0;
            *(us8*)&As[sar][sac + 8] = v1;
        }
        {
            int kg = kb + sbc;
            const u16* g = Wb + ((size_t)(kg >> 8) << 16) + (size_t)brow * DD + (kg & 255);
            us8 v0 = ((const us8*)g)[0], v1 = ((const us8*)g)[1];
            us8 v2 = ((const us8*)g)[2], v3 = ((const us8*)g)[3];
            *(us8*)&Bs[sbr][sbc]      = v0;
            *(us8*)&Bs[sbr][sbc + 8]  = v1;
            *(us8*)&Bs[sbr][sbc + 16] = v2;
            *(us8*)&Bs[sbr][sbc + 24] = v3;
        }
        __syncthreads();
        #pragma unroll
        for (int ks = 0; ks < 2; ++ks) {
            const int kk = ks * 32 + quad * 8;
            bf16x8 af[2], bfv[4];
            #pragma unroll
            for (int mt = 0; mt < 2; ++mt)
                af[mt] = __builtin_bit_cast(bf16x8, *(const us8*)&As[wr * 32 + mt * 16 + l15][kk]);
            #pragma unroll
            for (int nt = 0; nt < 4; ++nt)
                bfv[nt] = __builtin_bit_cast(bf16x8, *(const us8*)&Bs[wc * 64 + nt * 16 + l15][kk]);
            #pragma unroll
            for (int mt = 0; mt < 2; ++mt)
                #pragma unroll
                for (int nt = 0; nt < 4; ++nt)
                    acc[mt][nt] = __builtin_amdgcn_mfma_f32_16x16x32_bf16(
                        af[mt], bfv[nt], acc[mt][nt], 0, 0, 0);
        }
        __syncthreads();
    }

    // epilogue: relu + plain store (C/D layout: col=lane&15, row=quad*4+reg)
    #pragma unroll
    for (int nt = 0; nt < 4; ++nt) {
        const int n = n0 + wc * 64 + nt * 16 + l15;
        #pragma unroll
        for (int mt = 0; mt < 2; ++mt) {
            #pragma unroll
            for (int j = 0; j < 4; ++j) {
                const int m = wr * 32 + mt * 16 + quad * 4 + j;
                const int ml = m0 + m;
                if (ml < cs) out[(size_t)(d0 + ml) * DD + n] = fmaxf(acc[mt][nt][j], 0.0f);
            }
        }
    }
}

extern "C" void kernel_launch(void* const* d_in, const int* in_sizes, int n_in,
                              void* d_out, int out_size, void* d_ws, size_t ws_size,
                              hipStream_t stream) {
    const float* x      = (const float*)d_in[0];
    const int*   dep    = (const int*)  d_in[1];
    const int*   rel    = (const int*)  d_in[2];
    const int*   gov    = (const int*)  d_in[3];
    const float* W_self = (const float*)d_in[4];
    const float* b_self = (const float*)d_in[5];
    const float* W_rel  = (const float*)d_in[6];
    const float* b_rel  = (const float*)d_in[7];
    float* out = (float*)d_out;

    const int N  = in_sizes[0] / DD;     // 20000
    const int E  = in_sizes[1];          // 200000
    const int R2 = in_sizes[7] / DD;     // 24
    const int R  = R2 / 2;               // 12
    const int B  = N * R;                // 240000
    const int B2 = 2 * B;
    const int S  = R2 + 2;               // 26 slots
    const int K  = S * DD;               // 6656

    char* w = (char*)d_ws;
    auto alloc = [&](size_t bytes) {
        char* p = w;
        w += (bytes + 255) & ~(size_t)255;
        return p;
    };
    u16* xb     = (u16*)alloc((size_t)N * DD * sizeof(u16));
    u16* Wb     = (u16*)alloc((size_t)S * DD * DD * sizeof(u16));  // [0..2R)=W_rel, 2R=W_self, 2R+1=bias
    int* counts = (int*)alloc((size_t)B2 * sizeof(int));
    int* csr    = (int*)alloc((size_t)(B2 + 1) * sizeof(int));
    int* cursor = (int*)alloc((size_t)B2 * sizeof(int));
    int* bsum   = (int*)alloc((size_t)2048 * sizeof(int));
    int* bbase  = (int*)alloc((size_t)2048 * sizeof(int));
    int* edsrc  = (int*)alloc((size_t)2 * E * sizeof(int));

    // agg buffer: as many 64-row chunks as fit
    size_t used = (size_t)(w - (char*)d_ws);
    size_t avail = (ws_size > used) ? (ws_size - used) : 0;
    int Mpad = ((N + 63) / 64) * 64;
    int cap = (int)((avail / ((size_t)K * sizeof(u16))) / 64) * 64;
    if (cap > Mpad) cap = Mpad;
    if (cap < 64) cap = 64;
    u16* agg = (u16*)w;

    // 1. bf16 conversions + bias matrix
    k_convert<<<1024, 256, 0, stream>>>(x, xb, N * DD);
    k_convert<<<1024, 256, 0, stream>>>(W_rel, Wb, R2 * DD * DD);
    k_convert<<<64, 256, 0, stream>>>(W_self, Wb + (size_t)R2 * DD * DD, DD * DD);
    k_biasmat<<<DD, 256, 0, stream>>>(b_self, b_rel, Wb + (size_t)(R2 + 1) * DD * DD, R2);

    // 2. counting-sort edges by (dst, rel, dir) -> CSR + edsrc
    const int scanBlocks = (B2 + 255) / 256;
    k_zero<<<scanBlocks, 256, 0, stream>>>(counts, B2);
    k_hist2<<<256, 256, 0, stream>>>(dep, rel, gov, E, R, B, counts);
    k_scan1<<<scanBlocks, 256, 0, stream>>>(counts, csr, bsum, B2);
    k_scan2<<<1, 256, 0, stream>>>(bsum, bbase, scanBlocks);
    k_scan3<<<scanBlocks, 256, 0, stream>>>(csr, cursor, bbase, B2, 2 * E);
    k_sortscatter<<<(E + 255) / 256, 256, 0, stream>>>(dep, rel, gov, E, R, B, cursor, edsrc);

    // 3. per chunk: aggregate (d,s) buckets -> dense GEMM + bias + relu
    for (int d0 = 0; d0 < N; d0 += cap) {
        int cs = (N - d0 < cap) ? (N - d0) : cap;
        int halfwaves = cs * S;
        k_agg<<<(halfwaves + 7) / 8, 256, 0, stream>>>(xb, csr, edsrc, agg, d0, cs, R, B);
        dim3 g(2, (cs + 63) / 64, 1);
        k_dense<<<g, 256, 0, stream>>>(agg, Wb, out, d0, cs, K);
    }
}

// Round 6
// 401.828 us; speedup vs baseline: 1.4519x; 1.1549x over previous
//
#include <hip/hip_runtime.h>
#include <cstdint>
#include <cstddef>

#define DD 256
#define NSLOT 25      // 12 fwd rel | self | 12 rev rel
#define SELFSLOT 12

typedef unsigned short u16;
typedef __bf16 bf16t;
typedef bf16t bf16x8 __attribute__((ext_vector_type(8)));
typedef unsigned short us8 __attribute__((ext_vector_type(8)));
typedef unsigned short us4 __attribute__((ext_vector_type(4)));
typedef float f32x4 __attribute__((ext_vector_type(4)));

__device__ __forceinline__ u16 f2bf(float f) {
    uint32_t u = __builtin_bit_cast(uint32_t, f);
    u += 0x7FFFu + ((u >> 16) & 1u);   // RNE
    return (u16)(u >> 16);
}
__device__ __forceinline__ float bf2f(u16 h) {
    uint32_t u = ((uint32_t)h) << 16;
    return __builtin_bit_cast(float, u);
}

__global__ void k_convert(const float* __restrict__ s, u16* __restrict__ d, int n) {
    int i = blockIdx.x * blockDim.x + threadIdx.x;
    int st = gridDim.x * blockDim.x;
    for (; i < n; i += st) d[i] = f2bf(s[i]);
}

// bias_all[s][n]: s<12 -> b_rel[s], s==12 -> b_self, s>12 -> b_rel[s-1]
__global__ void k_bias(const float* __restrict__ b_self, const float* __restrict__ b_rel,
                       float* __restrict__ dst) {
    int i = blockIdx.x * 256 + threadIdx.x;
    if (i >= NSLOT * DD) return;
    int s = i >> 8, n = i & 255;
    float v;
    if (s < SELFSLOT) v = b_rel[s * DD + n];
    else if (s == SELFSLOT) v = b_self[n];
    else v = b_rel[(s - 1) * DD + n];
    dst[i] = v;
}

__global__ void k_zero(int* p, int n) {
    int i = blockIdx.x * blockDim.x + threadIdx.x;
    if (i < n) p[i] = 0;
}

// bucket key = group(slot)*N + dst;  fwd: slot=rel, dst=dep;  rev: slot=13+rel, dst=gov
__global__ void k_hist(const int* __restrict__ dep, const int* __restrict__ rel,
                       const int* __restrict__ gov, int E, int N, int SG,
                       int* __restrict__ cnt) {
    int i = blockIdx.x * blockDim.x + threadIdx.x;
    int st = gridDim.x * blockDim.x;
    for (; i < E; i += st) {
        int r = rel[i];
        int gf = r / SG;
        int gr = (13 + r) / SG;
        atomicAdd(&cnt[gf * N + dep[i]], 1);
        atomicAdd(&cnt[gr * N + gov[i]], 1);
    }
}

__global__ void k_scan1(const int* __restrict__ counts, int* __restrict__ csr,
                        int* __restrict__ bsum, int B2) {
    __shared__ int sm[256];
    int tid = threadIdx.x;
    int i = blockIdx.x * 256 + tid;
    int v = (i < B2) ? counts[i] : 0;
    sm[tid] = v;
    __syncthreads();
    for (int off = 1; off < 256; off <<= 1) {
        int t = (tid >= off) ? sm[tid - off] : 0;
        __syncthreads();
        sm[tid] += t;
        __syncthreads();
    }
    if (i < B2) csr[i] = sm[tid] - v;
    if (tid == 255) bsum[blockIdx.x] = sm[255];
}

__global__ void k_scan2(const int* __restrict__ bsum, int* __restrict__ bbase, int nb) {
    __shared__ int sm[256];
    int t = threadIdx.x;
    int pre[8];
    int tot = 0;
    for (int j = 0; j < 8; ++j) {
        int idx = t * 8 + j;
        int v = (idx < nb) ? bsum[idx] : 0;
        pre[j] = tot;
        tot += v;
    }
    sm[t] = tot;
    __syncthreads();
    for (int off = 1; off < 256; off <<= 1) {
        int x = (t >= off) ? sm[t - off] : 0;
        __syncthreads();
        sm[t] += x;
        __syncthreads();
    }
    int base = sm[t] - tot;
    for (int j = 0; j < 8; ++j) {
        int idx = t * 8 + j;
        if (idx < nb) bbase[idx] = base + pre[j];
    }
}

__global__ void k_scan3(int* __restrict__ csr, int* __restrict__ cursor,
                        const int* __restrict__ bbase, int B2, int E2) {
    int i = blockIdx.x * 256 + threadIdx.x;
    if (i < B2) {
        int v = csr[i] + bbase[i >> 8];
        csr[i] = v;
        cursor[i] = v;
    }
    if (i == 0) csr[B2] = E2;
}

// payload = src*32 + local_slot (slot - group*SG)
__global__ void k_scatter(const int* __restrict__ dep, const int* __restrict__ rel,
                          const int* __restrict__ gov, int E, int N, int SG,
                          int* __restrict__ cursor, int* __restrict__ epay) {
    int i = blockIdx.x * blockDim.x + threadIdx.x;
    int st = gridDim.x * blockDim.x;
    for (; i < E; i += st) {
        int r = rel[i], d = dep[i], g = gov[i];
        int gf = r / SG, slf = r - gf * SG;
        int sr = 13 + r;
        int gr = sr / SG, slr = sr - gr * SG;
        int p = atomicAdd(&cursor[gf * N + d], 1);
        epay[p] = (g << 5) | slf;
        int q = atomicAdd(&cursor[gr * N + g], 1);
        epay[q] = (d << 5) | slr;
    }
}

// Dense GEMM: T[m, n] = sum_k xb[m,k] * Wbase[n>>8][n&255][k] + bias[n], bf16 out.
// 64x128 tile, 256 thr = 4 waves (each 32 rows x 64 cols). grid(x=n-tiles, y=m-tiles).
__global__ __launch_bounds__(256) void k_T(
    const u16* __restrict__ xb, const u16* __restrict__ Wbase,
    const float* __restrict__ bias, u16* __restrict__ T, int M, int NG) {
    __shared__ u16 As[64][72];
    __shared__ u16 Bs[128][72];
    const int tid = threadIdx.x;
    const int n0 = blockIdx.x * 128;
    const int m0 = blockIdx.y * 64;
    const int lane = tid & 63, wv = tid >> 6;
    const int wr = wv & 1, wc = wv >> 1;
    const int l15 = lane & 15, quad = lane >> 4;

    // A staging: thread -> row tid>>2, 16-u16 chunk (tid&3)*16
    const int sar = tid >> 2, sac = (tid & 3) * 16;
    int arow = m0 + sar;
    if (arow >= M) arow = M - 1;          // clamp: only feeds discarded rows
    const u16* agp = xb + (size_t)arow * DD + sac;
    // B staging: thread -> row tid>>1, 32-u16 chunk (tid&1)*32
    const int sbr = tid >> 1, sbc = (tid & 1) * 32;
    const int nglob = n0 + sbr;
    const u16* bgp = Wbase + ((size_t)(nglob >> 8) << 16) + (size_t)(nglob & 255) * DD + sbc;

    f32x4 acc[2][4] = {};
    for (int kb = 0; kb < DD; kb += 64) {
        {
            const us8* g = (const us8*)(agp + kb);
            *(us8*)&As[sar][sac]     = g[0];
            *(us8*)&As[sar][sac + 8] = g[1];
        }
        {
            const us8* g = (const us8*)(bgp + kb);
            *(us8*)&Bs[sbr][sbc]      = g[0];
            *(us8*)&Bs[sbr][sbc + 8]  = g[1];
            *(us8*)&Bs[sbr][sbc + 16] = g[2];
            *(us8*)&Bs[sbr][sbc + 24] = g[3];
        }
        __syncthreads();
        #pragma unroll
        for (int ks = 0; ks < 2; ++ks) {
            const int kk = ks * 32 + quad * 8;
            bf16x8 af[2], bfv[4];
            #pragma unroll
            for (int mt = 0; mt < 2; ++mt)
                af[mt] = __builtin_bit_cast(bf16x8, *(const us8*)&As[wr * 32 + mt * 16 + l15][kk]);
            #pragma unroll
            for (int nt = 0; nt < 4; ++nt)
                bfv[nt] = __builtin_bit_cast(bf16x8, *(const us8*)&Bs[wc * 64 + nt * 16 + l15][kk]);
            #pragma unroll
            for (int mt = 0; mt < 2; ++mt)
                #pragma unroll
                for (int nt = 0; nt < 4; ++nt)
                    acc[mt][nt] = __builtin_amdgcn_mfma_f32_16x16x32_bf16(
                        af[mt], bfv[nt], acc[mt][nt], 0, 0, 0);
        }
        __syncthreads();   // also frees As/Bs for epilogue reuse
    }

    // epilogue: +bias, bf16, LDS transpose (reuse Bs), coalesced 64 B row stores
    float bv[4];
    #pragma unroll
    for (int nt = 0; nt < 4; ++nt) bv[nt] = bias[n0 + wc * 64 + nt * 16 + l15];
    u16* trb = &Bs[0][0] + wv * (32 * 72);   // per-wave 32 rows x 64 cols, stride 72
    #pragma unroll
    for (int nt = 0; nt < 4; ++nt)
        #pragma unroll
        for (int mt = 0; mt < 2; ++mt)
            #pragma unroll
            for (int j = 0; j < 4; ++j)
                trb[(mt * 16 + quad * 4 + j) * 72 + nt * 16 + l15] =
                    f2bf(acc[mt][nt][j] + bv[nt]);
    __syncthreads();
    const int row = lane >> 1, half = lane & 1;
    const int m = m0 + wr * 32 + row;
    if (m < M) {
        const us8* sp = (const us8*)(trb + row * 72 + half * 32);
        us8 v0 = sp[0], v1 = sp[1], v2 = sp[2], v3 = sp[3];
        us8* dp = (us8*)(T + (size_t)m * NG + n0 + wc * 64 + half * 32);
        dp[0] = v0; dp[1] = v1; dp[2] = v2; dp[3] = v3;
    }
}

// Gather: one wave per node; lane owns 4 feats. acc (fp32) = [prev out] + [self] + sum msgs.
__global__ __launch_bounds__(256) void k_gather(
    const u16* __restrict__ T, const int* __restrict__ epay,
    const int* __restrict__ csr, float* __restrict__ out,
    int N, int NG, int bktBase, int selfSl, int first, int last) {
    int wid = (blockIdx.x * 256 + threadIdx.x) >> 6;
    if (wid >= N) return;
    int feat = (threadIdx.x & 63) * 4;
    f32x4 a = {0.0f, 0.0f, 0.0f, 0.0f};
    if (!first) a = *(const f32x4*)(out + (size_t)wid * DD + feat);
    if (selfSl >= 0) {
        us4 v = *(const us4*)(T + (size_t)wid * NG + selfSl * DD + feat);
        a[0] += bf2f(v[0]); a[1] += bf2f(v[1]); a[2] += bf2f(v[2]); a[3] += bf2f(v[3]);
    }
    int beg = csr[bktBase + wid], end = csr[bktBase + wid + 1];
    f32x4 b = {0.0f, 0.0f, 0.0f, 0.0f};
    int j = beg;
    for (; j + 1 < end; j += 2) {
        int p0 = epay[j], p1 = epay[j + 1];
        us4 v0 = *(const us4*)(T + (size_t)(p0 >> 5) * NG + (p0 & 31) * DD + feat);
        us4 v1 = *(const us4*)(T + (size_t)(p1 >> 5) * NG + (p1 & 31) * DD + feat);
        a[0] += bf2f(v0[0]); a[1] += bf2f(v0[1]); a[2] += bf2f(v0[2]); a[3] += bf2f(v0[3]);
        b[0] += bf2f(v1[0]); b[1] += bf2f(v1[1]); b[2] += bf2f(v1[2]); b[3] += bf2f(v1[3]);
    }
    if (j < end) {
        int p0 = epay[j];
        us4 v0 = *(const us4*)(T + (size_t)(p0 >> 5) * NG + (p0 & 31) * DD + feat);
        a[0] += bf2f(v0[0]); a[1] += bf2f(v0[1]); a[2] += bf2f(v0[2]); a[3] += bf2f(v0[3]);
    }
    a[0] += b[0]; a[1] += b[1]; a[2] += b[2]; a[3] += b[3];
    if (last) {
        a[0] = fmaxf(a[0], 0.0f); a[1] = fmaxf(a[1], 0.0f);
        a[2] = fmaxf(a[2], 0.0f); a[3] = fmaxf(a[3], 0.0f);
    }
    *(f32x4*)(out + (size_t)wid * DD + feat) = a;
}

extern "C" void kernel_launch(void* const* d_in, const int* in_sizes, int n_in,
                              void* d_out, int out_size, void* d_ws, size_t ws_size,
                              hipStream_t stream) {
    const float* x      = (const float*)d_in[0];
    const int*   dep    = (const int*)  d_in[1];
    const int*   rel    = (const int*)  d_in[2];
    const int*   gov    = (const int*)  d_in[3];
    const float* W_self = (const float*)d_in[4];
    const float* b_self = (const float*)d_in[5];
    const float* W_rel  = (const float*)d_in[6];
    const float* b_rel  = (const float*)d_in[7];
    float* out = (float*)d_out;

    const int N  = in_sizes[0] / DD;     // 20000
    const int E  = in_sizes[1];          // 200000
    const int R2 = in_sizes[7] / DD;     // 24

    char* w = (char*)d_ws;
    auto alloc = [&](size_t bytes) {
        char* p = w;
        w += (bytes + 255) & ~(size_t)255;
        return p;
    };
    u16* xb   = (u16*)alloc((size_t)N * DD * sizeof(u16));
    u16* Wb   = (u16*)alloc((size_t)NSLOT * DD * DD * sizeof(u16));
    float* ba = (float*)alloc((size_t)NSLOT * DD * sizeof(float));
    int* cnt  = (int*)alloc((size_t)NSLOT * N * sizeof(int));     // worst-case groups
    int* csr  = (int*)alloc(((size_t)NSLOT * N + 1) * sizeof(int));
    int* cur  = (int*)alloc((size_t)NSLOT * N * sizeof(int));
    int* bsum = (int*)alloc((size_t)2048 * sizeof(int));
    int* bbas = (int*)alloc((size_t)2048 * sizeof(int));
    int* epay = (int*)alloc((size_t)2 * E * sizeof(int));

    // slot-group size from remaining workspace (T buffer = SG slots x N x 256 bf16)
    size_t used = (size_t)(w - (char*)d_ws);
    size_t avail = (ws_size > used) ? (ws_size - used) : 0;
    size_t slotBytes = (size_t)N * DD * sizeof(u16);   // 10.24 MB
    int SG = (int)(avail / slotBytes);
    if (SG > 13) SG = 13;                // 2 balanced passes max
    if (SG < 1) SG = 1;
    const int NGROUP = (NSLOT + SG - 1) / SG;
    const int B2 = NGROUP * N;
    u16* T = (u16*)w;

    // 1. converts: x; Wb slots [0..11]=W_rel fw, [12]=W_self, [13..24]=W_rel rev; bias table
    k_convert<<<1024, 256, 0, stream>>>(x, xb, N * DD);
    k_convert<<<1024, 256, 0, stream>>>(W_rel, Wb, 12 * DD * DD);
    k_convert<<<64, 256, 0, stream>>>(W_self, Wb + (size_t)SELFSLOT * DD * DD, DD * DD);
    k_convert<<<1024, 256, 0, stream>>>(W_rel + (size_t)12 * DD * DD,
                                        Wb + (size_t)13 * DD * DD, 12 * DD * DD);
    k_bias<<<(NSLOT * DD + 255) / 256, 256, 0, stream>>>(b_self, b_rel, ba);

    // 2. counting-sort edges by (slot-group, dst)
    const int scanBlocks = (B2 + 255) / 256;
    k_zero<<<scanBlocks, 256, 0, stream>>>(cnt, B2);
    k_hist<<<256, 256, 0, stream>>>(dep, rel, gov, E, N, SG, cnt);
    k_scan1<<<scanBlocks, 256, 0, stream>>>(cnt, csr, bsum, B2);
    k_scan2<<<1, 256, 0, stream>>>(bsum, bbas, scanBlocks);
    k_scan3<<<scanBlocks, 256, 0, stream>>>(csr, cur, bbas, B2, 2 * E);
    k_scatter<<<(E + 255) / 256, 256, 0, stream>>>(dep, rel, gov, E, N, SG, cur, epay);

    // 3. per slot-group: dense GEMM (bias folded) -> per-node gather-sum
    const int mTiles = (N + 63) / 64;
    const int gBlocks = (N + 3) / 4;
    for (int g = 0; g < NGROUP; ++g) {
        int s0 = g * SG;
        int NS = NSLOT - s0; if (NS > SG) NS = SG;
        int NG = NS * DD;
        k_T<<<dim3(NS * 2, mTiles), 256, 0, stream>>>(
            xb, Wb + (size_t)s0 * DD * DD, ba + (size_t)s0 * DD, T, N, NG);
        int selfSl = (SELFSLOT >= s0 && SELFSLOT < s0 + NS) ? (SELFSLOT - s0) : -1;
        k_gather<<<gBlocks, 256, 0, stream>>>(
            T, epay, csr, out, N, NG, g * N, selfSl,
            (g == 0) ? 1 : 0, (g == NGROUP - 1) ? 1 : 0);
    }
}

// Round 7
// 305.826 us; speedup vs baseline: 1.9077x; 1.3139x over previous
//
#include <hip/hip_runtime.h>
#include <cstdint>
#include <cstddef>

#define DD 256
#define NSLOT 25      // gslot: 0..11 fwd rel | 12 self | 13..24 rev rel
#define SELFSLOT 12

typedef unsigned short u16;
typedef __bf16 bf16t;
typedef bf16t bf16x8 __attribute__((ext_vector_type(8)));
typedef unsigned short us8 __attribute__((ext_vector_type(8)));
typedef unsigned short us4 __attribute__((ext_vector_type(4)));
typedef float f32x4 __attribute__((ext_vector_type(4)));

__device__ __forceinline__ u16 f2bf(float f) {
    uint32_t u = __builtin_bit_cast(uint32_t, f);
    u += 0x7FFFu + ((u >> 16) & 1u);   // RNE
    return (u16)(u >> 16);
}
__device__ __forceinline__ float bf2f(u16 h) {
    uint32_t u = ((uint32_t)h) << 16;
    return __builtin_bit_cast(float, u);
}

__global__ void k_convert(const float* __restrict__ s, u16* __restrict__ d, int n) {
    int i = blockIdx.x * blockDim.x + threadIdx.x;
    int st = gridDim.x * blockDim.x;
    for (; i < n; i += st) d[i] = f2bf(s[i]);
}

// bias_all[s][n]: s<12 -> b_rel[s], s==12 -> b_self, s>12 -> b_rel[s-1]
__global__ void k_bias(const float* __restrict__ b_self, const float* __restrict__ b_rel,
                       float* __restrict__ dst) {
    int i = blockIdx.x * 256 + threadIdx.x;
    if (i >= NSLOT * DD) return;
    int s = i >> 8, n = i & 255;
    float v;
    if (s < SELFSLOT) v = b_rel[s * DD + n];
    else if (s == SELFSLOT) v = b_self[n];
    else v = b_rel[(s - 1) * DD + n];
    dst[i] = v;
}

__global__ void k_zero(int* p, int n) {
    int i = blockIdx.x * blockDim.x + threadIdx.x;
    if (i < n) p[i] = 0;
}

// mark used (gslot, src) keys: fwd uses T[gov, rel], rev uses T[dep, 13+rel], self all nodes
__global__ void k_mark(const int* __restrict__ dep, const int* __restrict__ rel,
                       const int* __restrict__ gov, int E, int N, int* __restrict__ flag) {
    int i = blockIdx.x * blockDim.x + threadIdx.x;
    int st = gridDim.x * blockDim.x;
    for (int j = i; j < E; j += st) {
        int r = rel[j];
        flag[r * N + gov[j]] = 1;
        flag[(13 + r) * N + dep[j]] = 1;
    }
    for (int j = i; j < N; j += st) flag[SELFSLOT * N + j] = 1;
}

__global__ void k_scan1(const int* __restrict__ counts, int* __restrict__ csr,
                        int* __restrict__ bsum, int B2) {
    __shared__ int sm[256];
    int tid = threadIdx.x;
    int i = blockIdx.x * 256 + tid;
    int v = (i < B2) ? counts[i] : 0;
    sm[tid] = v;
    __syncthreads();
    for (int off = 1; off < 256; off <<= 1) {
        int t = (tid >= off) ? sm[tid - off] : 0;
        __syncthreads();
        sm[tid] += t;
        __syncthreads();
    }
    if (i < B2) csr[i] = sm[tid] - v;
    if (tid == 255) bsum[blockIdx.x] = sm[255];
}

__global__ void k_scan2(const int* __restrict__ bsum, int* __restrict__ bbase, int nb) {
    __shared__ int sm[256];
    int t = threadIdx.x;
    int pre[8];
    int tot = 0;
    for (int j = 0; j < 8; ++j) {
        int idx = t * 8 + j;
        int v = (idx < nb) ? bsum[idx] : 0;
        pre[j] = tot;
        tot += v;
    }
    sm[t] = tot;
    __syncthreads();
    for (int off = 1; off < 256; off <<= 1) {
        int x = (t >= off) ? sm[t - off] : 0;
        __syncthreads();
        sm[t] += x;
        __syncthreads();
    }
    int base = sm[t] - tot;
    for (int j = 0; j < 8; ++j) {
        int idx = t * 8 + j;
        if (idx < nb) bbase[idx] = base + pre[j];
    }
}

// finalize flag scan -> pos (exclusive), sentinel pos[B2] = total
__global__ void k_scan3f(int* __restrict__ pos, const int* __restrict__ bbase,
                         const int* __restrict__ flag, int B2) {
    int i = blockIdx.x * 256 + threadIdx.x;
    if (i < B2) {
        int v = pos[i] + bbase[i >> 8];
        pos[i] = v;
        if (i == B2 - 1) pos[B2] = v + flag[i];
    }
}

// finalize bucket scan -> csr + cursor, sentinel = E2
__global__ void k_scan3(int* __restrict__ csr, int* __restrict__ cursor,
                        const int* __restrict__ bbase, int B2, int E2) {
    int i = blockIdx.x * 256 + threadIdx.x;
    if (i < B2) {
        int v = csr[i] + bbase[i >> 8];
        csr[i] = v;
        cursor[i] = v;
    }
    if (i == 0) csr[B2] = E2;
}

// compacted row -> source node
__global__ void k_rk(const int* __restrict__ flag, const int* __restrict__ pos,
                     int* __restrict__ rksrc, int NN, int N) {
    int i = blockIdx.x * 256 + threadIdx.x;
    if (i >= NN) return;
    if (flag[i]) {
        int slot = i / N;
        rksrc[pos[i]] = i - slot * N;
    }
}

// histogram gather buckets by (group, dst)
__global__ void k_hist(const int* __restrict__ dep, const int* __restrict__ rel,
                       const int* __restrict__ gov, int E, int N, int SG,
                       int* __restrict__ cnt) {
    int i = blockIdx.x * blockDim.x + threadIdx.x;
    int st = gridDim.x * blockDim.x;
    for (; i < E; i += st) {
        int r = rel[i];
        atomicAdd(&cnt[(r / SG) * N + dep[i]], 1);
        atomicAdd(&cnt[((13 + r) / SG) * N + gov[i]], 1);
    }
}

// payload = group-local compacted T row
__global__ void k_scatter(const int* __restrict__ dep, const int* __restrict__ rel,
                          const int* __restrict__ gov, int E, int N, int SG,
                          const int* __restrict__ pos,
                          int* __restrict__ cursor, int* __restrict__ epay) {
    int i = blockIdx.x * blockDim.x + threadIdx.x;
    int st = gridDim.x * blockDim.x;
    for (; i < E; i += st) {
        int r = rel[i], d = dep[i], g = gov[i];
        int g0 = r / SG;
        int p = atomicAdd(&cursor[g0 * N + d], 1);
        epay[p] = pos[r * N + g] - pos[g0 * SG * N];
        int gs = 13 + r;
        int g1 = gs / SG;
        int q = atomicAdd(&cursor[g1 * N + g], 1);
        epay[q] = pos[gs * N + d] - pos[g1 * SG * N];
    }
}

// Compacted GEMM: for each used row (src,gslot): T[row,:] = x[src] . W[gslot]^T + bias[gslot]
// 128x128 tile (4 waves x 64x64), K=256. grid.x = Sg*tilesPerSlot (slot-major), grid.y = 2 n-tiles.
__global__ __launch_bounds__(256) void k_T(
    const u16* __restrict__ xb, const u16* __restrict__ Wb, const float* __restrict__ ba,
    const int* __restrict__ pos, const int* __restrict__ rksrc, u16* __restrict__ T,
    int N, int gslot0, int tilesPerSlot) {
    __shared__ u16 sm[2 * 128 * 72];     // As = sm, Bs = sm + 128*72; reused for transpose
    __shared__ int s_src[128];
    u16 (*As)[72] = (u16(*)[72])sm;
    u16 (*Bs)[72] = (u16(*)[72])(sm + 128 * 72);

    const int bx = blockIdx.x;
    const int slot = bx / tilesPerSlot;
    const int mtile = bx - slot * tilesPerSlot;
    const int gslot = gslot0 + slot;
    const int u0 = pos[gslot * N];
    const int used = pos[(gslot + 1) * N] - u0;
    const int row0 = mtile * 128;
    if (row0 >= used) return;
    const int gbase = pos[gslot0 * N];
    const int n0 = blockIdx.y * 128;
    const int tid = threadIdx.x;

    if (tid < 128) {
        int r = row0 + tid;
        s_src[tid] = rksrc[u0 + ((r < used) ? r : (used - 1))];
    }
    __syncthreads();

    const int lane = tid & 63, wv = tid >> 6;
    const int wr = wv & 1, wc = wv >> 1;
    const int l15 = lane & 15, quad = lane >> 4;
    const int srow = tid >> 1, sh = (tid & 1) * 32;
    const u16* bgp = Wb + ((size_t)gslot << 16) + (size_t)(n0 + srow) * DD + sh;

    f32x4 acc[4][4] = {};
    for (int kb = 0; kb < DD; kb += 64) {
        {
            const us8* ga = (const us8*)(xb + (size_t)s_src[srow] * DD + kb + sh);
            us8 a0 = ga[0], a1 = ga[1], a2 = ga[2], a3 = ga[3];
            *(us8*)&As[srow][sh]      = a0;
            *(us8*)&As[srow][sh + 8]  = a1;
            *(us8*)&As[srow][sh + 16] = a2;
            *(us8*)&As[srow][sh + 24] = a3;
            const us8* gb = (const us8*)(bgp + kb);
            us8 b0 = gb[0], b1 = gb[1], b2 = gb[2], b3 = gb[3];
            *(us8*)&Bs[srow][sh]      = b0;
            *(us8*)&Bs[srow][sh + 8]  = b1;
            *(us8*)&Bs[srow][sh + 16] = b2;
            *(us8*)&Bs[srow][sh + 24] = b3;
        }
        __syncthreads();
        #pragma unroll
        for (int ks = 0; ks < 2; ++ks) {
            const int kk = ks * 32 + quad * 8;
            bf16x8 af[4], bfv[4];
            #pragma unroll
            for (int mt = 0; mt < 4; ++mt)
                af[mt] = __builtin_bit_cast(bf16x8, *(const us8*)&As[wr * 64 + mt * 16 + l15][kk]);
            #pragma unroll
            for (int nt = 0; nt < 4; ++nt)
                bfv[nt] = __builtin_bit_cast(bf16x8, *(const us8*)&Bs[wc * 64 + nt * 16 + l15][kk]);
            #pragma unroll
            for (int mt = 0; mt < 4; ++mt)
                #pragma unroll
                for (int nt = 0; nt < 4; ++nt)
                    acc[mt][nt] = __builtin_amdgcn_mfma_f32_16x16x32_bf16(
                        af[mt], bfv[nt], acc[mt][nt], 0, 0, 0);
        }
        __syncthreads();
    }

    // epilogue: +bias, bf16, per-wave LDS transpose, 64 B contiguous stores
    float bv[4];
    #pragma unroll
    for (int nt = 0; nt < 4; ++nt) bv[nt] = ba[gslot * DD + n0 + wc * 64 + nt * 16 + l15];
    u16* trb = sm + wv * (64 * 72);   // 64 rows x 64 cols, stride 72
    #pragma unroll
    for (int nt = 0; nt < 4; ++nt)
        #pragma unroll
        for (int mt = 0; mt < 4; ++mt)
            #pragma unroll
            for (int j = 0; j < 4; ++j)
                trb[(mt * 16 + quad * 4 + j) * 72 + nt * 16 + l15] =
                    f2bf(acc[mt][nt][j] + bv[nt]);
    __syncthreads();
    const int trow0 = u0 - gbase + row0 + wr * 64;
    const int half = lane & 1;
    #pragma unroll
    for (int it = 0; it < 2; ++it) {
        int r = it * 32 + (lane >> 1);
        if (row0 + wr * 64 + r < used) {
            const us8* sp = (const us8*)(trb + r * 72 + half * 32);
            us8 v0 = sp[0], v1 = sp[1], v2 = sp[2], v3 = sp[3];
            us8* dp = (us8*)(T + (size_t)(trow0 + r) * DD + n0 + wc * 64 + half * 32);
            dp[0] = v0; dp[1] = v1; dp[2] = v2; dp[3] = v3;
        }
    }
}

// Gather: one wave per node; lane owns 4 feats; payload = compacted T row.
__global__ __launch_bounds__(256) void k_gather(
    const u16* __restrict__ T, const int* __restrict__ epay,
    const int* __restrict__ csr, const int* __restrict__ pos,
    float* __restrict__ out, int N, int bktBase, int selfKeyBase, int gfN,
    int first, int last) {
    int wid = (blockIdx.x * 256 + threadIdx.x) >> 6;
    if (wid >= N) return;
    int feat = (threadIdx.x & 63) * 4;
    f32x4 a = {0.0f, 0.0f, 0.0f, 0.0f};
    if (!first) a = *(const f32x4*)(out + (size_t)wid * DD + feat);
    if (selfKeyBase >= 0) {
        int p = pos[selfKeyBase + wid] - pos[gfN];
        us4 v = *(const us4*)(T + (size_t)p * DD + feat);
        a[0] += bf2f(v[0]); a[1] += bf2f(v[1]); a[2] += bf2f(v[2]); a[3] += bf2f(v[3]);
    }
    int beg = csr[bktBase + wid], end = csr[bktBase + wid + 1];
    f32x4 b = {0.0f, 0.0f, 0.0f, 0.0f};
    int j = beg;
    for (; j + 1 < end; j += 2) {
        int p0 = epay[j], p1 = epay[j + 1];
        us4 v0 = *(const us4*)(T + (size_t)p0 * DD + feat);
        us4 v1 = *(const us4*)(T + (size_t)p1 * DD + feat);
        a[0] += bf2f(v0[0]); a[1] += bf2f(v0[1]); a[2] += bf2f(v0[2]); a[3] += bf2f(v0[3]);
        b[0] += bf2f(v1[0]); b[1] += bf2f(v1[1]); b[2] += bf2f(v1[2]); b[3] += bf2f(v1[3]);
    }
    if (j < end) {
        int p0 = epay[j];
        us4 v0 = *(const us4*)(T + (size_t)p0 * DD + feat);
        a[0] += bf2f(v0[0]); a[1] += bf2f(v0[1]); a[2] += bf2f(v0[2]); a[3] += bf2f(v0[3]);
    }
    a[0] += b[0]; a[1] += b[1]; a[2] += b[2]; a[3] += b[3];
    if (last) {
        a[0] = fmaxf(a[0], 0.0f); a[1] = fmaxf(a[1], 0.0f);
        a[2] = fmaxf(a[2], 0.0f); a[3] = fmaxf(a[3], 0.0f);
    }
    *(f32x4*)(out + (size_t)wid * DD + feat) = a;
}

extern "C" void kernel_launch(void* const* d_in, const int* in_sizes, int n_in,
                              void* d_out, int out_size, void* d_ws, size_t ws_size,
                              hipStream_t stream) {
    const float* x      = (const float*)d_in[0];
    const int*   dep    = (const int*)  d_in[1];
    const int*   rel    = (const int*)  d_in[2];
    const int*   gov    = (const int*)  d_in[3];
    const float* W_self = (const float*)d_in[4];
    const float* b_self = (const float*)d_in[5];
    const float* W_rel  = (const float*)d_in[6];
    const float* b_rel  = (const float*)d_in[7];
    float* out = (float*)d_out;

    const int N  = in_sizes[0] / DD;     // 20000
    const int E  = in_sizes[1];          // 200000
    const int NN = NSLOT * N;            // 500000 keys

    char* w = (char*)d_ws;
    auto alloc = [&](size_t bytes) {
        char* p = w;
        w += (bytes + 255) & ~(size_t)255;
        return p;
    };
    u16* xb    = (u16*)alloc((size_t)N * DD * sizeof(u16));
    u16* Wb    = (u16*)alloc((size_t)NSLOT * DD * DD * sizeof(u16));
    float* ba  = (float*)alloc((size_t)NSLOT * DD * sizeof(float));
    int* flag  = (int*)alloc((size_t)NN * sizeof(int));           // aliased later as bucket cnt
    int* pos   = (int*)alloc(((size_t)NN + 1) * sizeof(int));
    int* rksrc = (int*)alloc(((size_t)2 * E + N) * sizeof(int));
    int* bcsr  = (int*)alloc(((size_t)6 * N + 1) * sizeof(int));
    int* bcur  = (int*)alloc((size_t)6 * N * sizeof(int));
    int* bsum  = (int*)alloc((size_t)2048 * sizeof(int));
    int* bbas  = (int*)alloc((size_t)2048 * sizeof(int));
    int* epay  = (int*)alloc((size_t)2 * E * sizeof(int));

    size_t used = (size_t)(w - (char*)d_ws);
    size_t avail = (ws_size > used) ? (ws_size - used) : 0;

    // choose group count: tight worst-case T rows per group
    int NGROUP = 2, SG = 13;
    for (int ng = 1; ng <= 5; ++ng) {
        int sg = (NSLOT + ng - 1) / ng;
        size_t maxB = 0;
        for (int g = 0; g < ng; ++g) {
            int s0 = g * sg, s1 = s0 + sg; if (s1 > NSLOT) s1 = NSLOT;
            if (s0 >= NSLOT) break;
            int hasSelf = (s0 <= SELFSLOT && SELFSLOT < s1) ? 1 : 0;
            size_t rels = (size_t)(s1 - s0 - hasSelf);
            size_t rows = rels * N; if (rows > (size_t)2 * E) rows = (size_t)2 * E;
            rows += hasSelf ? (size_t)N : 0;
            if (rows > maxB) maxB = rows;
        }
        if (maxB * ((size_t)DD * 2) <= avail) { NGROUP = ng; SG = sg; break; }
        NGROUP = ng + 1; SG = (NSLOT + NGROUP - 1) / NGROUP;
    }
    u16* T = (u16*)w;

    // 1. converts + bias table
    k_convert<<<1024, 256, 0, stream>>>(x, xb, N * DD);
    k_convert<<<1024, 256, 0, stream>>>(W_rel, Wb, 12 * DD * DD);
    k_convert<<<64, 256, 0, stream>>>(W_self, Wb + (size_t)SELFSLOT * DD * DD, DD * DD);
    k_convert<<<1024, 256, 0, stream>>>(W_rel + (size_t)12 * DD * DD,
                                        Wb + (size_t)13 * DD * DD, 12 * DD * DD);
    k_bias<<<(NSLOT * DD + 255) / 256, 256, 0, stream>>>(b_self, b_rel, ba);

    // 2. compaction: flag used (gslot,src) keys -> pos -> rksrc
    const int fBlocks = (NN + 255) / 256;
    k_zero<<<fBlocks, 256, 0, stream>>>(flag, NN);
    k_mark<<<512, 256, 0, stream>>>(dep, rel, gov, E, N, flag);
    k_scan1<<<fBlocks, 256, 0, stream>>>(flag, pos, bsum, NN);
    k_scan2<<<1, 256, 0, stream>>>(bsum, bbas, fBlocks);
    k_scan3f<<<fBlocks, 256, 0, stream>>>(pos, bbas, flag, NN);
    k_rk<<<fBlocks, 256, 0, stream>>>(flag, pos, rksrc, NN, N);

    // 3. gather-bucket sort by (group, dst); payload = compacted row (flag reused as cnt)
    int* bcnt = flag;
    const int B2 = NGROUP * N;
    const int bBlocks = (B2 + 255) / 256;
    k_zero<<<bBlocks, 256, 0, stream>>>(bcnt, B2);
    k_hist<<<256, 256, 0, stream>>>(dep, rel, gov, E, N, SG, bcnt);
    k_scan1<<<bBlocks, 256, 0, stream>>>(bcnt, bcsr, bsum, B2);
    k_scan2<<<1, 256, 0, stream>>>(bsum, bbas, bBlocks);
    k_scan3<<<bBlocks, 256, 0, stream>>>(bcsr, bcur, bbas, B2, 2 * E);
    k_scatter<<<(E + 255) / 256, 256, 0, stream>>>(dep, rel, gov, E, N, SG, pos, bcur, epay);

    // 4. per group: compacted GEMM -> per-node gather-sum (+relu on last)
    const int tilesPerSlot = (N + 127) / 128;
    const int gBlocks = (N + 3) / 4;
    for (int g = 0; g < NGROUP; ++g) {
        int s0 = g * SG;
        if (s0 >= NSLOT) break;
        int Sg = NSLOT - s0; if (Sg > SG) Sg = SG;
        k_T<<<dim3(Sg * tilesPerSlot, 2), 256, 0, stream>>>(
            xb, Wb, ba, pos, rksrc, T, N, s0, tilesPerSlot);
        int hasSelf = (s0 <= SELFSLOT && SELFSLOT < s0 + Sg);
        k_gather<<<gBlocks, 256, 0, stream>>>(
            T, epay, bcsr, pos, out, N, g * N,
            hasSelf ? SELFSLOT * N : -1, s0 * N,
            (g == 0) ? 1 : 0, (g == NGROUP - 1) ? 1 : 0);
    }
}